// Round 6
// baseline (542.640 us; speedup 1.0000x reference)
//
#include <hip/hip_runtime.h>
#include <cstdint>
#include <cstddef>

// ---------------------------------------------------------------------------
// TemporalGNN: 2x EvolveGCNH (TopK-pool -> GRU weight evolve -> GCNConv) + MLP
// N=100000 nodes, F=128, E=625000 edges, all fp32.
// R6: 4-col gather waves (16 row-loads in flight), merged setup kernels,
//     LDS-based block-sum scan, rstart[N+1] CSR.
// ---------------------------------------------------------------------------

#define FDIM 128

typedef __attribute__((ext_vector_type(8))) short bfrag;   // 8 bf16 (4 VGPRs)
typedef __attribute__((ext_vector_type(4))) float f32x4;

__device__ __forceinline__ float wave_sum(float v) {
#pragma unroll
  for (int m = 32; m >= 1; m >>= 1) v += __shfl_xor(v, m, 64);
  return v;
}

__device__ __forceinline__ float sigmoidf_(float x) {
  return 1.0f / (1.0f + expf(-x));
}

// monotone float->uint map (order-preserving)
__device__ __forceinline__ unsigned omap(float f) {
  unsigned u = __float_as_uint(f);
  return (u & 0x80000000u) ? ~u : (u | 0x80000000u);
}

// xcd-chunked block remap (requires gridDim.x % 8 == 0): each XCD gets a
// contiguous slab of effective block ids -> L2 locality for node slabs.
__device__ __forceinline__ int xcd_chunk(int b, int nb) {
  return (b & 7) * (nb >> 3) + (b >> 3);
}

// ---------------- setup: degree, CSR build -----------------------------------

__global__ void k_init_degcnt(float* deg, int* cnt, int* csel1, int* csel2, int n) {
  int i = blockIdx.x * blockDim.x + threadIdx.x;
  if (i < n) { deg[i] = 1.0f; cnt[i] = 0; }   // self-loop weight 1 pre-added
  if (i == 0) { csel1[0] = 0; csel2[0] = 0; }
}

__global__ void k_edge_deg(const int* __restrict__ ei, const float* __restrict__ ew,
                           float* deg, int* cnt, int E) {
  int e = blockIdx.x * blockDim.x + threadIdx.x;
  if (e < E) {
    int c = ei[E + e];                         // col
    atomicAdd(&deg[c], ew[e]);
    atomicAdd(&cnt[c], 1);
  }
}

// block sums for cnt (1024/block) + dinv computation (merged)
__global__ void k_scan1(const int* __restrict__ cnt, int* bsum,
                        const float* __restrict__ deg, float* __restrict__ dinv, int n) {
  __shared__ int s[256];
  int b = blockIdx.x, t = threadIdx.x;
  int base = b * 1024;
  int v = 0;
#pragma unroll
  for (int j = 0; j < 4; j++) {
    int i = base + j * 256 + t;
    if (i < n) { v += cnt[i]; dinv[i] = 1.0f / sqrtf(deg[i]); }
  }
  s[t] = v; __syncthreads();
  for (int off = 128; off > 0; off >>= 1) { if (t < off) s[t] += s[t + off]; __syncthreads(); }
  if (t == 0) bsum[b] = s[0];
}

// exclusive scan of bsum in LDS + rstart[N]=E + tiny per-layer setup (merged)
__global__ __launch_bounds__(128) void k_scan2_setup(
    int* bsum, int nb, int* rstartN,
    const float* p1, const float* p2, float* invn1, float* invn2,
    const float* l1w, const float* l1b, const float* l2w, const float* l2b,
    float* v, float* cc) {
  __shared__ int s[1024];
  int t = threadIdx.x;
  for (int i = t; i < nb; i += 128) s[i] = bsum[i];
  __syncthreads();
  if (t == 0) {
    int run = 0;
    for (int b = 0; b < nb; b++) { int x = s[b]; s[b] = run; run += x; }
    s[1023] = run;                      // total edge count (nb << 1023 here)
  }
  __syncthreads();
  for (int i = t; i < nb; i += 128) bsum[i] = s[i];
  if (t == 0) rstartN[0] = s[1023];
  // per-layer tiny setup
  int wv = t >> 6, l = t & 63;
  const float* p = wv ? p2 : p1;
  float2 pv = ((const float2*)p)[l];
  float ss = wave_sum(pv.x * pv.x + pv.y * pv.y);
  if (l == 0) (wv ? invn2 : invn1)[0] = 1.0f / sqrtf(ss);
  v[t] = l2w[0] * l1w[t] + l2w[1] * l1w[128 + t];
  if (t == 0) cc[0] = l2w[0] * l1b[0] + l2w[1] * l1b[1] + l2b[0];
}

__global__ __launch_bounds__(1024) void k_scan3(const int* __restrict__ cnt,
                                                const int* __restrict__ bsum,
                                                int* rstart, int* rnext, int n) {
  __shared__ int s[1024];
  int b = blockIdx.x, t = threadIdx.x;
  int i = b * 1024 + t;
  int v = (i < n) ? cnt[i] : 0;
  s[t] = v; __syncthreads();
  for (int off = 1; off < 1024; off <<= 1) {
    int tmp = (t >= off) ? s[t - off] : 0;
    __syncthreads();
    s[t] += tmp;
    __syncthreads();
  }
  if (i < n) { int ex = bsum[b] + s[t] - v; rstart[i] = ex; rnext[i] = ex; }
}

// scatter edge payload (row, norm) into CSR slots
__global__ void k_fill(const int* __restrict__ ei, const float* __restrict__ ew,
                       const float* __restrict__ dinv, int* rnext, int2* pay, int E) {
  int e = blockIdx.x * blockDim.x + threadIdx.x;
  if (e < E) {
    int r = ei[e];
    int c = ei[E + e];
    float nm = dinv[r] * ew[e] * dinv[c];
    int pos = atomicAdd(&rnext[c], 1);
    pay[pos] = make_int2(r, __float_as_int(nm));
  }
}

// ---------------- scores (16 contiguous rows / wave) -------------------------

__global__ void k_score(const float* __restrict__ x, const float* __restrict__ p,
                        const float* __restrict__ invn, float* __restrict__ sc, int n) {
  int l = threadIdx.x & 63;
  int eb = xcd_chunk(blockIdx.x, gridDim.x);
  int w = eb * 4 + (threadIdx.x >> 6);
  int base = w * 16;
  if (base >= n) return;
  float2 pv = ((const float2*)p)[l];
  float inv = invn[0];
  if (base + 16 <= n) {
#pragma unroll
    for (int r = 0; r < 16; r++) {
      float2 a = ((const float2*)(x + (size_t)(base + r) * FDIM))[l];
      float s = wave_sum(a.x * pv.x + a.y * pv.y);
      if (l == 0) sc[base + r] = s * inv;
    }
  } else {
    for (int r = 0; r < n - base; r++) {
      float2 a = ((const float2*)(x + (size_t)(base + r) * FDIM))[l];
      float s = wave_sum(a.x * pv.x + a.y * pv.y);
      if (l == 0) sc[base + r] = s * inv;
    }
  }
}

// ---------------- top-k via sampled threshold --------------------------------

__global__ __launch_bounds__(1024) void k_sample(const float* __restrict__ sc, int n,
                                                 float* __restrict__ thr) {
  __shared__ float a[2048];
  int t = threadIdx.x;
  int stride = n / 2048;
#pragma unroll
  for (int j = 0; j < 2; j++) a[j * 1024 + t] = sc[(size_t)(j * 1024 + t) * stride];
  for (int size = 2; size <= 2048; size <<= 1) {
    for (int st = size >> 1; st > 0; st >>= 1) {
      __syncthreads();
      for (int i = t; i < 2048; i += 1024) {
        int j = i ^ st;
        if (j > i) {
          float xv = a[i], yv = a[j];
          bool up = ((i & size) == 0);
          if (up ? (xv < yv) : (xv > yv)) { a[i] = yv; a[j] = xv; }
        }
      }
    }
  }
  __syncthreads();
  if (t == 0) thr[0] = a[15];
}

__global__ void k_collect(const float* __restrict__ sc, const float* __restrict__ thr,
                          unsigned long long* candk, int* csel, int n) {
  int i = blockIdx.x * blockDim.x + threadIdx.x;
  if (i >= n) return;
  float s = sc[i];
  if (s >= thr[0]) {
    int pos = atomicAdd(csel, 1);
    if (pos < 4096)
      candk[pos] = ((unsigned long long)omap(s) << 32) | (unsigned)(~(unsigned)i);
  }
}

// sort candidates (desc, index-asc tiebreak baked into key), emit top 128
__global__ __launch_bounds__(1024) void k_sel(const unsigned long long* __restrict__ candk,
                                              const int* __restrict__ csel,
                                              int* tidx, float* ttanh) {
  __shared__ unsigned long long a[4096];
  int t = threadIdx.x;
  int nc = csel[0]; if (nc > 4096) nc = 4096;
  int M = 128; while (M < nc) M <<= 1;
  for (int i = t; i < M; i += 1024) a[i] = (i < nc) ? candk[i] : 0ULL;
  for (int size = 2; size <= M; size <<= 1) {
    for (int stride = size >> 1; stride > 0; stride >>= 1) {
      __syncthreads();
      for (int i = t; i < M; i += 1024) {
        int j = i ^ stride;
        if (j > i) {
          unsigned long long x = a[i], y = a[j];
          bool up = ((i & size) == 0);
          if (up ? (x < y) : (x > y)) { a[i] = y; a[j] = x; }
        }
      }
    }
  }
  __syncthreads();
  if (t < 128) {
    unsigned long long k = a[t];
    unsigned idx = ~(unsigned)k;
    unsigned hi = (unsigned)(k >> 32);
    unsigned u = (hi & 0x80000000u) ? (hi ^ 0x80000000u) : ~hi;
    tidx[t] = (int)idx;
    ttanh[t] = tanhf(__uint_as_float(u));
  }
}

// ---------------- GRU weight evolve -> bf16-split transposed weights --------

__global__ __launch_bounds__(384) void k_gru(const float* __restrict__ xin,
                                             const int* __restrict__ tidx,
                                             const float* __restrict__ ttanh,
                                             const float* __restrict__ wih,
                                             const float* __restrict__ whh,
                                             const float* __restrict__ bih,
                                             const float* __restrict__ bhh,
                                             const float* __restrict__ h0,
                                             unsigned short* __restrict__ WT_hi,
                                             unsigned short* __restrict__ WT_lo) {
  __shared__ float xt[128], hs[128], gis[384], ghs[384];
  int r = blockIdx.x, t = threadIdx.x;
  if (t < 128) {
    int idx = tidx[r];
    xt[t] = xin[(size_t)idx * FDIM + t] * ttanh[r];
    hs[t] = h0[r * FDIM + t];
  }
  __syncthreads();
  float gi = bih[t], gh = bhh[t];
  const float4* wi4 = (const float4*)(wih + (size_t)t * FDIM);
  const float4* wh4 = (const float4*)(whh + (size_t)t * FDIM);
#pragma unroll 8
  for (int k = 0; k < 32; k++) {
    float4 av = wi4[k], bv = wh4[k];
    gi += av.x * xt[4 * k] + av.y * xt[4 * k + 1] + av.z * xt[4 * k + 2] + av.w * xt[4 * k + 3];
    gh += bv.x * hs[4 * k] + bv.y * hs[4 * k + 1] + bv.z * hs[4 * k + 2] + bv.w * hs[4 * k + 3];
  }
  gis[t] = gi; ghs[t] = gh;
  __syncthreads();
  if (t < 128) {
    float rg = sigmoidf_(gis[t] + ghs[t]);
    float zg = sigmoidf_(gis[t + 128] + ghs[t + 128]);
    float ng = tanhf(gis[t + 256] + rg * ghs[t + 256]);
    float w = (1.0f - zg) * ng + zg * hs[t];
    unsigned u = __float_as_uint(w);
    float res = w - __uint_as_float(u & 0xFFFF0000u);
    WT_hi[t * FDIM + r] = (unsigned short)(u >> 16);
    WT_lo[t * FDIM + r] = (unsigned short)(__float_as_uint(res) >> 16);
  }
}

// ---------------- big GEMM via MFMA: Y[N,128] = X[N,128] @ W[128,128] -------

__global__ __launch_bounds__(256) void k_gemm3(const float* __restrict__ X,
                                               const unsigned short* __restrict__ BTh,
                                               const unsigned short* __restrict__ BTl,
                                               float* __restrict__ Y, int nrows) {
  int tid = threadIdx.x;
  int wv = tid >> 6, l = tid & 63;
  int eb = xcd_chunk(blockIdx.x, gridDim.x);
  int tile = eb * 4 + wv;
  int ntiles = (nrows + 15) >> 4;
  if (tile >= ntiles) return;
  int r0 = tile * 16;
  int arow = r0 + (l & 15);
  if (arow >= nrows) arow = nrows - 1;     // clamp; guarded at store
  int kgrp = (l >> 4) * 8;

  f32x4 acc[8];
#pragma unroll
  for (int c = 0; c < 8; c++) acc[c] = (f32x4){0.f, 0.f, 0.f, 0.f};

  const float* xp = X + (size_t)arow * FDIM + kgrp;

#pragma unroll
  for (int ks = 0; ks < 4; ks++) {
    float4 v0 = *(const float4*)(xp + ks * 32);
    float4 v1 = *(const float4*)(xp + ks * 32 + 4);
    float xs[8] = {v0.x, v0.y, v0.z, v0.w, v1.x, v1.y, v1.z, v1.w};
    bfrag ah, al;
#pragma unroll
    for (int i = 0; i < 8; i++) {
      unsigned u = __float_as_uint(xs[i]);
      float res = xs[i] - __uint_as_float(u & 0xFFFF0000u);
      ah[i] = (short)(u >> 16);
      al[i] = (short)(__float_as_uint(res) >> 16);
    }
#pragma unroll
    for (int ct = 0; ct < 8; ct++) {
      size_t boff = (size_t)(ct * 16 + (l & 15)) * FDIM + ks * 32 + kgrp;
      bfrag bh = *(const bfrag*)(BTh + boff);
      bfrag bl = *(const bfrag*)(BTl + boff);
      acc[ct] = __builtin_amdgcn_mfma_f32_16x16x32_bf16(ah, bh, acc[ct], 0, 0, 0);
      acc[ct] = __builtin_amdgcn_mfma_f32_16x16x32_bf16(ah, bl, acc[ct], 0, 0, 0);
      acc[ct] = __builtin_amdgcn_mfma_f32_16x16x32_bf16(al, bh, acc[ct], 0, 0, 0);
    }
  }
  int rbase = r0 + (l >> 4) * 4;
#pragma unroll
  for (int ct = 0; ct < 8; ct++) {
    int col = ct * 16 + (l & 15);
#pragma unroll
    for (int r = 0; r < 4; r++) {
      int row = rbase + r;
      if (row < nrows) Y[(size_t)row * FDIM + col] = acc[ct][r];
    }
  }
}

// ---------------- GCN gather: 4 cols/wave, 16 row-loads in flight ------------
// FUSE=0: write h1 + layer-2 score.  FUSE=1: final MLP to out.  XCD-chunked.

template <int FUSE>
__global__ __launch_bounds__(256) void k_gather(
    const float* __restrict__ xw, const float* __restrict__ dinv,
    const int* __restrict__ rstart,          // N+1 entries (rstart[N]=E)
    const int2* __restrict__ pay, float* __restrict__ outH, float* __restrict__ outF,
    const float* __restrict__ p2, const float* __restrict__ invn2,
    float* __restrict__ sc, const float* __restrict__ vvec, const float* __restrict__ cc,
    int n) {
  int wv = threadIdx.x >> 6, l = threadIdx.x & 63;
  int eb = xcd_chunk(blockIdx.x, gridDim.x);
  int c0 = (eb * 4 + wv) * 4;
  if (c0 >= n) return;
  int sts[5];
#pragma unroll
  for (int i = 0; i < 5; i++) sts[i] = rstart[min(c0 + i, n)];
  float2 acc[4];
#pragma unroll
  for (int i = 0; i < 4; i++) {
    int c = c0 + i;
    if (c < n) {
      float dc = dinv[c];
      float2 v = ((const float2*)(xw + (size_t)c * FDIM))[l];
      acc[i] = make_float2(dc * dc * v.x, dc * dc * v.y);
    } else {
      acc[i] = make_float2(0.f, 0.f);
    }
  }
  int stBase = sts[0];
  int total = sts[4] - stBase;
  for (int cb = 0; cb < total; cb += 64) {
    // one coalesced payload load covers up to 64 edges across the 4 cols;
    // out-of-range lanes pad with (row c0, weight 0) -> safe, masked anyway
    int2 ep = (cb + l < total) ? pay[stBase + cb + l] : make_int2(c0, 0);
#pragma unroll
    for (int sub = 0; sub < 4; sub++) {
      int q0 = cb + sub * 16;
      if (q0 >= total) break;
      int rr[16]; float nm[16];
#pragma unroll
      for (int u = 0; u < 16; u++) {
        rr[u] = __shfl(ep.x, sub * 16 + u, 64);
        nm[u] = __int_as_float(__shfl(ep.y, sub * 16 + u, 64));
      }
      float2 ev[16];
#pragma unroll
      for (int u = 0; u < 16; u++)
        ev[u] = ((const float2*)(xw + (size_t)rr[u] * FDIM))[l];
#pragma unroll
      for (int u = 0; u < 16; u++) {
        int g = stBase + q0 + u;
#pragma unroll
        for (int i = 0; i < 4; i++) {
          float wi = (g >= sts[i] && g < sts[i + 1]) ? nm[u] : 0.0f;
          acc[i].x += wi * ev[u].x;
          acc[i].y += wi * ev[u].y;
        }
      }
    }
  }
  float s0, s1, s2, s3;
  {
    float2 wvv = (FUSE == 0) ? ((const float2*)p2)[l] : ((const float2*)vvec)[l];
#pragma unroll
    for (int i = 0; i < 4; i++) {
      float r0 = fmaxf(acc[i].x, 0.0f), r1 = fmaxf(acc[i].y, 0.0f);
      if (FUSE == 0 && c0 + i < n)
        ((float2*)(outH + (size_t)(c0 + i) * FDIM))[l] = make_float2(r0, r1);
      float s = wave_sum(r0 * wvv.x + r1 * wvv.y);
      if (i == 0) s0 = s; else if (i == 1) s1 = s; else if (i == 2) s2 = s; else s3 = s;
    }
  }
  float sv = (l == 0) ? s0 : (l == 1) ? s1 : (l == 2) ? s2 : s3;
  if (l < 4 && c0 + l < n) {
    if (FUSE == 0) sc[c0 + l] = sv * invn2[0];
    else outF[c0 + l] = sv + cc[0];
  }
}

// ---------------------------------------------------------------------------

extern "C" void kernel_launch(void* const* d_in, const int* in_sizes, int n_in,
                              void* d_out, int out_size, void* d_ws, size_t ws_size,
                              hipStream_t stream) {
  const float* x    = (const float*)d_in[0];
  const int*   ei   = (const int*)d_in[1];
  const float* ew   = (const float*)d_in[2];
  const float* p1   = (const float*)d_in[3];
  const float* wih1 = (const float*)d_in[4];
  const float* whh1 = (const float*)d_in[5];
  const float* bih1 = (const float*)d_in[6];
  const float* bhh1 = (const float*)d_in[7];
  const float* h01  = (const float*)d_in[8];
  const float* p2   = (const float*)d_in[9];
  const float* wih2 = (const float*)d_in[10];
  const float* whh2 = (const float*)d_in[11];
  const float* bih2 = (const float*)d_in[12];
  const float* bhh2 = (const float*)d_in[13];
  const float* h02  = (const float*)d_in[14];
  const float* l1w  = (const float*)d_in[15];
  const float* l1b  = (const float*)d_in[16];
  const float* l2w  = (const float*)d_in[17];
  const float* l2b  = (const float*)d_in[18];
  float* out = (float*)d_out;

  const int N = in_sizes[0] / FDIM;
  const int E = in_sizes[2];

  // workspace layout
  size_t off = 0;
  auto alloc = [&](size_t bytes) -> char* {
    char* p = (char*)d_ws + off;
    off = (off + bytes + 255) & ~(size_t)255;
    return p;
  };
  float* scores = (float*)alloc((size_t)N * 4);
  unsigned long long* candk = (unsigned long long*)alloc(4096 * 8);
  int*   tidx  = (int*)alloc(128 * 4);
  float* ttanh = (float*)alloc(128 * 4);
  float* invn1 = (float*)alloc(4);
  float* invn2 = (float*)alloc(4);
  float* thr1  = (float*)alloc(4);
  float* thr2  = (float*)alloc(4);
  float* deg   = (float*)alloc((size_t)N * 4);
  float* dinv  = (float*)alloc((size_t)N * 4);
  int*   cnt   = (int*)alloc((size_t)N * 4);
  int*   rstart= (int*)alloc((size_t)(N + 1) * 4);
  int*   rnext = (int*)alloc((size_t)N * 4);
  const int nb = (N + 1023) / 1024;
  int*   bsum  = (int*)alloc((size_t)nb * 4);
  int2*  pay   = (int2*)alloc((size_t)E * 8);
  float* vvec  = (float*)alloc(128 * 4);
  float* cc    = (float*)alloc(4);
  unsigned short* WTh = (unsigned short*)alloc(128 * 128 * 2);
  unsigned short* WTl = (unsigned short*)alloc(128 * 128 * 2);
  int*   csel1 = (int*)alloc(8);
  int*   csel2 = (int*)alloc(8);
  float* xw    = (float*)alloc((size_t)N * FDIM * 4);
  float* h1    = (float*)alloc((size_t)N * FDIM * 4);
  (void)ws_size; (void)n_in; (void)out_size;

  const int gemmblocks   = (((N + 15) / 16 + 3) / 4 + 7) & ~7;   // mult of 8
  const int scoreblocks  = gemmblocks;
  const int gatherblocks = (((N + 15) / 16) + 7) & ~7;           // 16 cols/block

  // ---- setup: degrees + CSR payload (shared by both layers) ----
  k_init_degcnt<<<(N + 255) / 256, 256, 0, stream>>>(deg, cnt, csel1, csel2, N);
  k_edge_deg<<<(E + 255) / 256, 256, 0, stream>>>(ei, ew, deg, cnt, E);
  k_scan1<<<nb, 256, 0, stream>>>(cnt, bsum, deg, dinv, N);
  k_scan2_setup<<<1, 128, 0, stream>>>(bsum, nb, rstart + N, p1, p2, invn1, invn2,
                                       l1w, l1b, l2w, l2b, vvec, cc);
  k_scan3<<<nb, 1024, 0, stream>>>(cnt, bsum, rstart, rnext, N);
  k_fill<<<(E + 255) / 256, 256, 0, stream>>>(ei, ew, dinv, rnext, pay, E);

  // ---- layer 1 ----
  k_score<<<scoreblocks, 256, 0, stream>>>(x, p1, invn1, scores, N);
  k_sample<<<1, 1024, 0, stream>>>(scores, N, thr1);
  k_collect<<<(N + 255) / 256, 256, 0, stream>>>(scores, thr1, candk, csel1, N);
  k_sel<<<1, 1024, 0, stream>>>(candk, csel1, tidx, ttanh);
  k_gru<<<128, 384, 0, stream>>>(x, tidx, ttanh, wih1, whh1, bih1, bhh1, h01, WTh, WTl);
  k_gemm3<<<gemmblocks, 256, 0, stream>>>(x, WTh, WTl, xw, N);
  k_gather<0><<<gatherblocks, 256, 0, stream>>>(xw, dinv, rstart, pay, h1, nullptr,
                                                p2, invn2, scores, nullptr, nullptr, N);

  // ---- layer 2 + fused final linear ----
  k_sample<<<1, 1024, 0, stream>>>(scores, N, thr2);
  k_collect<<<(N + 255) / 256, 256, 0, stream>>>(scores, thr2, candk, csel2, N);
  k_sel<<<1, 1024, 0, stream>>>(candk, csel2, tidx, ttanh);
  k_gru<<<128, 384, 0, stream>>>(h1, tidx, ttanh, wih2, whh2, bih2, bhh2, h02, WTh, WTl);
  k_gemm3<<<gemmblocks, 256, 0, stream>>>(h1, WTh, WTl, xw, N);
  k_gather<1><<<gatherblocks, 256, 0, stream>>>(xw, dinv, rstart, pay, nullptr, out,
                                                nullptr, nullptr, nullptr, vvec, cc, N);
}

// Round 7
// 436.377 us; speedup vs baseline: 1.2435x; 1.2435x over previous
//
#include <hip/hip_runtime.h>
#include <cstdint>
#include <cstddef>

// ---------------------------------------------------------------------------
// TemporalGNN: 2x EvolveGCNH (TopK-pool -> GRU weight evolve -> GCNConv) + MLP
// N=100000 nodes, F=128, E=625000 edges, all fp32.
// R7: GEMM with LDS-staged B (kills 1.6GB L2 re-read), gather reverted to R5
//     form (3.2TB/s plateau), layer-1 score array dropped (sampdots+fused
//     score/collect), init via memset.
// ---------------------------------------------------------------------------

#define FDIM 128

typedef __attribute__((ext_vector_type(8))) short bfrag;   // 8 bf16 (4 VGPRs)
typedef __attribute__((ext_vector_type(4))) float f32x4;

__device__ __forceinline__ float wave_sum(float v) {
#pragma unroll
  for (int m = 32; m >= 1; m >>= 1) v += __shfl_xor(v, m, 64);
  return v;
}

__device__ __forceinline__ float sigmoidf_(float x) {
  return 1.0f / (1.0f + expf(-x));
}

// monotone float->uint map (order-preserving)
__device__ __forceinline__ unsigned omap(float f) {
  unsigned u = __float_as_uint(f);
  return (u & 0x80000000u) ? ~u : (u | 0x80000000u);
}

// xcd-chunked block remap (requires gridDim.x % 8 == 0)
__device__ __forceinline__ int xcd_chunk(int b, int nb) {
  return (b & 7) * (nb >> 3) + (b >> 3);
}

// LDS byte swizzle: row stride 256B, XOR col bits 4-6 with row&7 -> 2-way max
__device__ __forceinline__ int swz(int row, int colb) {
  return row * 256 + (colb ^ ((row & 7) << 4));
}

// ---------------- setup: degree, CSR build -----------------------------------

__global__ void k_edge_deg(const int* __restrict__ ei, const float* __restrict__ ew,
                           float* deg, int* cnt, int E) {
  int e = blockIdx.x * blockDim.x + threadIdx.x;
  if (e < E) {
    int c = ei[E + e];                         // col
    atomicAdd(&deg[c], ew[e]);
    atomicAdd(&cnt[c], 1);
  }
}

// block sums for cnt (1024/block) + dinv = rsqrt(1 + sum(w)) (self-loop)
__global__ void k_scan1(const int* __restrict__ cnt, int* bsum,
                        const float* __restrict__ deg, float* __restrict__ dinv, int n) {
  __shared__ int s[256];
  int b = blockIdx.x, t = threadIdx.x;
  int base = b * 1024;
  int v = 0;
#pragma unroll
  for (int j = 0; j < 4; j++) {
    int i = base + j * 256 + t;
    if (i < n) { v += cnt[i]; dinv[i] = 1.0f / sqrtf(1.0f + deg[i]); }
  }
  s[t] = v; __syncthreads();
  for (int off = 128; off > 0; off >>= 1) { if (t < off) s[t] += s[t + off]; __syncthreads(); }
  if (t == 0) bsum[b] = s[0];
}

// exclusive scan of bsum in LDS + rstart[N]=E + tiny per-layer setup (merged)
__global__ __launch_bounds__(128) void k_scan2_setup(
    int* bsum, int nb, int* rstartN,
    const float* p1, const float* p2, float* invn1, float* invn2,
    const float* l1w, const float* l1b, const float* l2w, const float* l2b,
    float* v, float* cc) {
  __shared__ int s[1024];
  int t = threadIdx.x;
  for (int i = t; i < nb; i += 128) s[i] = bsum[i];
  __syncthreads();
  if (t == 0) {
    int run = 0;
    for (int b = 0; b < nb; b++) { int x = s[b]; s[b] = run; run += x; }
    s[1023] = run;
  }
  __syncthreads();
  for (int i = t; i < nb; i += 128) bsum[i] = s[i];
  if (t == 0) rstartN[0] = s[1023];
  int wv = t >> 6, l = t & 63;
  const float* p = wv ? p2 : p1;
  float2 pv = ((const float2*)p)[l];
  float ss = wave_sum(pv.x * pv.x + pv.y * pv.y);
  if (l == 0) (wv ? invn2 : invn1)[0] = 1.0f / sqrtf(ss);
  v[t] = l2w[0] * l1w[t] + l2w[1] * l1w[128 + t];
  if (t == 0) cc[0] = l2w[0] * l1b[0] + l2w[1] * l1b[1] + l2b[0];
}

__global__ __launch_bounds__(1024) void k_scan3(const int* __restrict__ cnt,
                                                const int* __restrict__ bsum,
                                                int* rstart, int* rnext, int n) {
  __shared__ int s[1024];
  int b = blockIdx.x, t = threadIdx.x;
  int i = b * 1024 + t;
  int v = (i < n) ? cnt[i] : 0;
  s[t] = v; __syncthreads();
  for (int off = 1; off < 1024; off <<= 1) {
    int tmp = (t >= off) ? s[t - off] : 0;
    __syncthreads();
    s[t] += tmp;
    __syncthreads();
  }
  if (i < n) { int ex = bsum[b] + s[t] - v; rstart[i] = ex; rnext[i] = ex; }
}

// scatter edge payload (row, norm) into CSR slots
__global__ void k_fill(const int* __restrict__ ei, const float* __restrict__ ew,
                       const float* __restrict__ dinv, int* rnext, int2* pay, int E) {
  int e = blockIdx.x * blockDim.x + threadIdx.x;
  if (e < E) {
    int r = ei[e];
    int c = ei[E + e];
    float nm = dinv[r] * ew[e] * dinv[c];
    int pos = atomicAdd(&rnext[c], 1);
    pay[pos] = make_int2(r, __float_as_int(nm));
  }
}

// ---------------- top-k: sample dots -> thr -> fused score+collect -> sel ----

// 2048 strided rows of x dotted with p (exact same reduction as scorecollect)
__global__ void k_sampdots(const float* __restrict__ x, const float* __restrict__ p,
                           const float* __restrict__ invn, float* __restrict__ samp,
                           int stride) {
  int l = threadIdx.x & 63;
  int w = blockIdx.x * 4 + (threadIdx.x >> 6);   // 0..511
  float2 pv = ((const float2*)p)[l];
  float inv = invn[0];
#pragma unroll
  for (int r = 0; r < 4; r++) {
    int si = w * 4 + r;
    float2 a = ((const float2*)(x + (size_t)(si * stride) * FDIM))[l];
    float s = wave_sum(a.x * pv.x + a.y * pv.y) * inv;
    if (l == 0) samp[si] = s;
  }
}

// bitonic sort 2048 samples desc, thr = 16th largest
__global__ __launch_bounds__(1024) void k_thr(const float* __restrict__ samp,
                                              float* __restrict__ thr) {
  __shared__ float a[2048];
  int t = threadIdx.x;
  a[t] = samp[t]; a[t + 1024] = samp[t + 1024];
  for (int size = 2; size <= 2048; size <<= 1) {
    for (int st = size >> 1; st > 0; st >>= 1) {
      __syncthreads();
      for (int i = t; i < 2048; i += 1024) {
        int j = i ^ st;
        if (j > i) {
          float xv = a[i], yv = a[j];
          bool up = ((i & size) == 0);
          if (up ? (xv < yv) : (xv > yv)) { a[i] = yv; a[j] = xv; }
        }
      }
    }
  }
  __syncthreads();
  if (t == 0) thr[0] = a[15];
}

// score all rows, collect >= thr directly (no score array)
__global__ void k_scorecollect(const float* __restrict__ x, const float* __restrict__ p,
                               const float* __restrict__ invn, const float* __restrict__ thr,
                               unsigned long long* __restrict__ candk, int* __restrict__ csel,
                               int n) {
  int l = threadIdx.x & 63;
  int eb = xcd_chunk(blockIdx.x, gridDim.x);
  int base = (eb * 4 + (threadIdx.x >> 6)) * 16;
  if (base >= n) return;
  float2 pv = ((const float2*)p)[l];
  float inv = invn[0], th = thr[0];
  int lim = min(16, n - base);
  for (int r = 0; r < lim; r++) {
    float2 a = ((const float2*)(x + (size_t)(base + r) * FDIM))[l];
    float s = wave_sum(a.x * pv.x + a.y * pv.y) * inv;
    if (l == 0 && s >= th) {
      int pos = atomicAdd(csel, 1);
      if (pos < 4096)
        candk[pos] = ((unsigned long long)omap(s) << 32) | (unsigned)(~(unsigned)(base + r));
    }
  }
}

// layer-2: thr from strided samples of the sc array (written by gather<0>)
__global__ __launch_bounds__(1024) void k_sample(const float* __restrict__ sc, int n,
                                                 float* __restrict__ thr) {
  __shared__ float a[2048];
  int t = threadIdx.x;
  int stride = n / 2048;
#pragma unroll
  for (int j = 0; j < 2; j++) a[j * 1024 + t] = sc[(size_t)(j * 1024 + t) * stride];
  for (int size = 2; size <= 2048; size <<= 1) {
    for (int st = size >> 1; st > 0; st >>= 1) {
      __syncthreads();
      for (int i = t; i < 2048; i += 1024) {
        int j = i ^ st;
        if (j > i) {
          float xv = a[i], yv = a[j];
          bool up = ((i & size) == 0);
          if (up ? (xv < yv) : (xv > yv)) { a[i] = yv; a[j] = xv; }
        }
      }
    }
  }
  __syncthreads();
  if (t == 0) thr[0] = a[15];
}

__global__ void k_collect(const float* __restrict__ sc, const float* __restrict__ thr,
                          unsigned long long* candk, int* csel, int n) {
  int i = blockIdx.x * blockDim.x + threadIdx.x;
  if (i >= n) return;
  float s = sc[i];
  if (s >= thr[0]) {
    int pos = atomicAdd(csel, 1);
    if (pos < 4096)
      candk[pos] = ((unsigned long long)omap(s) << 32) | (unsigned)(~(unsigned)i);
  }
}

// sort candidates (desc, index-asc tiebreak baked into key), emit top 128
__global__ __launch_bounds__(1024) void k_sel(const unsigned long long* __restrict__ candk,
                                              const int* __restrict__ csel,
                                              int* tidx, float* ttanh) {
  __shared__ unsigned long long a[4096];
  int t = threadIdx.x;
  int nc = csel[0]; if (nc > 4096) nc = 4096;
  int M = 128; while (M < nc) M <<= 1;
  for (int i = t; i < M; i += 1024) a[i] = (i < nc) ? candk[i] : 0ULL;
  for (int size = 2; size <= M; size <<= 1) {
    for (int stride = size >> 1; stride > 0; stride >>= 1) {
      __syncthreads();
      for (int i = t; i < M; i += 1024) {
        int j = i ^ stride;
        if (j > i) {
          unsigned long long x = a[i], y = a[j];
          bool up = ((i & size) == 0);
          if (up ? (x < y) : (x > y)) { a[i] = y; a[j] = x; }
        }
      }
    }
  }
  __syncthreads();
  if (t < 128) {
    unsigned long long k = a[t];
    unsigned idx = ~(unsigned)k;
    unsigned hi = (unsigned)(k >> 32);
    unsigned u = (hi & 0x80000000u) ? (hi ^ 0x80000000u) : ~hi;
    tidx[t] = (int)idx;
    ttanh[t] = tanhf(__uint_as_float(u));
  }
}

// ---------------- GRU weight evolve -> bf16-split transposed weights --------

__global__ __launch_bounds__(384) void k_gru(const float* __restrict__ xin,
                                             const int* __restrict__ tidx,
                                             const float* __restrict__ ttanh,
                                             const float* __restrict__ wih,
                                             const float* __restrict__ whh,
                                             const float* __restrict__ bih,
                                             const float* __restrict__ bhh,
                                             const float* __restrict__ h0,
                                             unsigned short* __restrict__ WT_hi,
                                             unsigned short* __restrict__ WT_lo) {
  __shared__ float xt[128], hs[128], gis[384], ghs[384];
  int r = blockIdx.x, t = threadIdx.x;
  if (t < 128) {
    int idx = tidx[r];
    xt[t] = xin[(size_t)idx * FDIM + t] * ttanh[r];
    hs[t] = h0[r * FDIM + t];
  }
  __syncthreads();
  float gi = bih[t], gh = bhh[t];
  const float4* wi4 = (const float4*)(wih + (size_t)t * FDIM);
  const float4* wh4 = (const float4*)(whh + (size_t)t * FDIM);
#pragma unroll 8
  for (int k = 0; k < 32; k++) {
    float4 av = wi4[k], bv = wh4[k];
    gi += av.x * xt[4 * k] + av.y * xt[4 * k + 1] + av.z * xt[4 * k + 2] + av.w * xt[4 * k + 3];
    gh += bv.x * hs[4 * k] + bv.y * hs[4 * k + 1] + bv.z * hs[4 * k + 2] + bv.w * hs[4 * k + 3];
  }
  gis[t] = gi; ghs[t] = gh;
  __syncthreads();
  if (t < 128) {
    float rg = sigmoidf_(gis[t] + ghs[t]);
    float zg = sigmoidf_(gis[t + 128] + ghs[t + 128]);
    float ng = tanhf(gis[t + 256] + rg * ghs[t + 256]);
    float w = (1.0f - zg) * ng + zg * hs[t];
    unsigned u = __float_as_uint(w);
    float res = w - __uint_as_float(u & 0xFFFF0000u);
    WT_hi[t * FDIM + r] = (unsigned short)(u >> 16);
    WT_lo[t * FDIM + r] = (unsigned short)(__float_as_uint(res) >> 16);
  }
}

// ---------------- GEMM via MFMA with LDS-staged B ---------------------------
// Y[N,128] = X @ W; 3-pass bf16 split. Block = 4 waves, 128 rows (2x16/wave).
// B (WTh+WTl, 64KB) staged once per block, XOR-swizzled -> 2-way max conflict.

__global__ __launch_bounds__(256) void k_gemm4(const float* __restrict__ X,
                                               const unsigned short* __restrict__ BTh,
                                               const unsigned short* __restrict__ BTl,
                                               float* __restrict__ Y, int nrows) {
  __shared__ unsigned short sBh[128 * 128];   // 32 KB
  __shared__ unsigned short sBl[128 * 128];   // 32 KB
  int tid = threadIdx.x;
  int eb = xcd_chunk(blockIdx.x, gridDim.x);
  int rblk = eb * 128;
  if (rblk >= nrows) return;
  // stage B: 2048 uint4 per array, swizzled
  for (int i = tid; i < 2048; i += 256) {
    int row = i >> 4, colb = (i & 15) << 4;
    *(uint4*)((char*)sBh + swz(row, colb)) = ((const uint4*)BTh)[i];
    *(uint4*)((char*)sBl + swz(row, colb)) = ((const uint4*)BTl)[i];
  }
  __syncthreads();
  int wv = tid >> 6, l = tid & 63;
  int lcol = l & 15;
  int kgrp = (l >> 4) * 8;

  for (int tile = 0; tile < 2; tile++) {
    int r0 = rblk + wv * 32 + tile * 16;
    if (r0 >= nrows) break;
    int arow = min(r0 + lcol, nrows - 1);
    f32x4 acc[8];
#pragma unroll
    for (int c = 0; c < 8; c++) acc[c] = (f32x4){0.f, 0.f, 0.f, 0.f};
    const float* xp = X + (size_t)arow * FDIM + kgrp;
#pragma unroll
    for (int ks = 0; ks < 4; ks++) {
      float4 v0 = *(const float4*)(xp + ks * 32);
      float4 v1 = *(const float4*)(xp + ks * 32 + 4);
      float xs[8] = {v0.x, v0.y, v0.z, v0.w, v1.x, v1.y, v1.z, v1.w};
      bfrag ah, al;
#pragma unroll
      for (int i = 0; i < 8; i++) {
        unsigned u = __float_as_uint(xs[i]);
        float res = xs[i] - __uint_as_float(u & 0xFFFF0000u);
        ah[i] = (short)(u >> 16);
        al[i] = (short)(__float_as_uint(res) >> 16);
      }
      int colb = (ks * 32 + kgrp) * 2;
#pragma unroll
      for (int ct = 0; ct < 8; ct++) {
        int off = swz(ct * 16 + lcol, colb);
        bfrag bh = *(const bfrag*)((const char*)sBh + off);
        bfrag bl = *(const bfrag*)((const char*)sBl + off);
        acc[ct] = __builtin_amdgcn_mfma_f32_16x16x32_bf16(ah, bh, acc[ct], 0, 0, 0);
        acc[ct] = __builtin_amdgcn_mfma_f32_16x16x32_bf16(ah, bl, acc[ct], 0, 0, 0);
        acc[ct] = __builtin_amdgcn_mfma_f32_16x16x32_bf16(al, bh, acc[ct], 0, 0, 0);
      }
    }
    int rbase = r0 + (l >> 4) * 4;
#pragma unroll
    for (int ct = 0; ct < 8; ct++) {
      int col = ct * 16 + lcol;
#pragma unroll
      for (int r = 0; r < 4; r++) {
        int row = rbase + r;
        if (row < nrows) Y[(size_t)row * FDIM + col] = acc[ct][r];
      }
    }
  }
}

// ---------------- GCN gather (R5 form: 1 col/wave) + fused epilogues ---------

template <int FUSE>
__global__ void k_gather(const float* __restrict__ xw, const float* __restrict__ dinv,
                         const int* __restrict__ rstart,    // N+1
                         const int2* __restrict__ pay, float* __restrict__ outH,
                         float* __restrict__ outF,
                         const float* __restrict__ p2, const float* __restrict__ invn2,
                         float* __restrict__ sc,
                         const float* __restrict__ vvec, const float* __restrict__ cc,
                         int n) {
  int wv = threadIdx.x >> 6, l = threadIdx.x & 63;
  int eb = xcd_chunk(blockIdx.x, gridDim.x);
  int c = eb * 4 + wv;
  if (c >= n) return;
  float dc = dinv[c];
  float2 v = ((const float2*)(xw + (size_t)c * FDIM))[l];
  float ax = dc * dc * v.x, ay = dc * dc * v.y;
  int st = rstart[c], cn = rstart[c + 1] - st;
  for (int q0 = 0; q0 < cn; q0 += 64) {
    int2 ep = (q0 + l < cn) ? pay[st + q0 + l] : make_int2(0, 0);
    int m = min(64, cn - q0);
    for (int q = 0; q < m; q++) {
      int r = __shfl(ep.x, q, 64);
      float nm = __int_as_float(__shfl(ep.y, q, 64));
      float2 s = ((const float2*)(xw + (size_t)r * FDIM))[l];
      ax += nm * s.x; ay += nm * s.y;
    }
  }
  float r0 = fmaxf(ax, 0.0f), r1 = fmaxf(ay, 0.0f);
  if (FUSE == 0) {
    ((float2*)(outH + (size_t)c * FDIM))[l] = make_float2(r0, r1);
    float2 pv = ((const float2*)p2)[l];
    float s = wave_sum(r0 * pv.x + r1 * pv.y);
    if (l == 0) sc[c] = s * invn2[0];
  } else {
    float2 vv = ((const float2*)vvec)[l];
    float s = wave_sum(r0 * vv.x + r1 * vv.y);
    if (l == 0) outF[c] = s + cc[0];
  }
}

// ---------------------------------------------------------------------------

extern "C" void kernel_launch(void* const* d_in, const int* in_sizes, int n_in,
                              void* d_out, int out_size, void* d_ws, size_t ws_size,
                              hipStream_t stream) {
  const float* x    = (const float*)d_in[0];
  const int*   ei   = (const int*)d_in[1];
  const float* ew   = (const float*)d_in[2];
  const float* p1   = (const float*)d_in[3];
  const float* wih1 = (const float*)d_in[4];
  const float* whh1 = (const float*)d_in[5];
  const float* bih1 = (const float*)d_in[6];
  const float* bhh1 = (const float*)d_in[7];
  const float* h01  = (const float*)d_in[8];
  const float* p2   = (const float*)d_in[9];
  const float* wih2 = (const float*)d_in[10];
  const float* whh2 = (const float*)d_in[11];
  const float* bih2 = (const float*)d_in[12];
  const float* bhh2 = (const float*)d_in[13];
  const float* h02  = (const float*)d_in[14];
  const float* l1w  = (const float*)d_in[15];
  const float* l1b  = (const float*)d_in[16];
  const float* l2w  = (const float*)d_in[17];
  const float* l2b  = (const float*)d_in[18];
  float* out = (float*)d_out;

  const int N = in_sizes[0] / FDIM;
  const int E = in_sizes[2];

  // workspace layout
  size_t off = 0;
  auto alloc = [&](size_t bytes) -> char* {
    char* p = (char*)d_ws + off;
    off = (off + bytes + 255) & ~(size_t)255;
    return p;
  };
  // zero-init region (one memset): deg, cnt, csel1/2
  float* deg   = (float*)alloc((size_t)N * 4);
  int*   cnt   = (int*)alloc((size_t)N * 4);
  int*   csel1 = (int*)alloc(8);
  int*   csel2 = (int*)alloc(8);
  size_t zero_span = (size_t)((char*)(csel2 + 2) - (char*)deg);
  // rest
  float* scores = (float*)alloc((size_t)N * 4);     // layer-2 sc only
  unsigned long long* candk = (unsigned long long*)alloc(4096 * 8);
  int*   tidx  = (int*)alloc(128 * 4);
  float* ttanh = (float*)alloc(128 * 4);
  float* invn1 = (float*)alloc(4);
  float* invn2 = (float*)alloc(4);
  float* thr1  = (float*)alloc(4);
  float* thr2  = (float*)alloc(4);
  float* samp  = (float*)alloc(2048 * 4);
  float* dinv  = (float*)alloc((size_t)N * 4);
  int*   rstart= (int*)alloc((size_t)(N + 1) * 4);
  int*   rnext = (int*)alloc((size_t)N * 4);
  const int nb = (N + 1023) / 1024;
  int*   bsum  = (int*)alloc((size_t)nb * 4);
  int2*  pay   = (int2*)alloc((size_t)E * 8);
  float* vvec  = (float*)alloc(128 * 4);
  float* cc    = (float*)alloc(4);
  unsigned short* WTh = (unsigned short*)alloc(128 * 128 * 2);
  unsigned short* WTl = (unsigned short*)alloc(128 * 128 * 2);
  float* xw    = (float*)alloc((size_t)N * FDIM * 4);
  float* h1    = (float*)alloc((size_t)N * FDIM * 4);
  (void)ws_size; (void)n_in; (void)out_size;

  const int scoreblocks  = (((N + 15) / 16 + 3) / 4 + 7) & ~7;   // mult of 8
  const int gemmblocks   = ((N + 127) / 128 + 7) & ~7;           // 128 rows/blk
  const int gatherblocks = (N + 3) / 4;                          // %8 == 0
  const int sampstride   = N / 2048;

  // ---- setup ----
  hipMemsetAsync(deg, 0, zero_span, stream);
  k_edge_deg<<<(E + 255) / 256, 256, 0, stream>>>(ei, ew, deg, cnt, E);
  k_scan1<<<nb, 256, 0, stream>>>(cnt, bsum, deg, dinv, N);
  k_scan2_setup<<<1, 128, 0, stream>>>(bsum, nb, rstart + N, p1, p2, invn1, invn2,
                                       l1w, l1b, l2w, l2b, vvec, cc);
  k_scan3<<<nb, 1024, 0, stream>>>(cnt, bsum, rstart, rnext, N);
  k_fill<<<(E + 255) / 256, 256, 0, stream>>>(ei, ew, dinv, rnext, pay, E);

  // ---- layer 1 ----
  k_sampdots<<<128, 256, 0, stream>>>(x, p1, invn1, samp, sampstride);
  k_thr<<<1, 1024, 0, stream>>>(samp, thr1);
  k_scorecollect<<<scoreblocks, 256, 0, stream>>>(x, p1, invn1, thr1, candk, csel1, N);
  k_sel<<<1, 1024, 0, stream>>>(candk, csel1, tidx, ttanh);
  k_gru<<<128, 384, 0, stream>>>(x, tidx, ttanh, wih1, whh1, bih1, bhh1, h01, WTh, WTl);
  k_gemm4<<<gemmblocks, 256, 0, stream>>>(x, WTh, WTl, xw, N);
  k_gather<0><<<gatherblocks, 256, 0, stream>>>(xw, dinv, rstart, pay, h1, nullptr,
                                                p2, invn2, scores, nullptr, nullptr, N);

  // ---- layer 2 + fused final linear ----
  k_sample<<<1, 1024, 0, stream>>>(scores, N, thr2);
  k_collect<<<(N + 255) / 256, 256, 0, stream>>>(scores, thr2, candk, csel2, N);
  k_sel<<<1, 1024, 0, stream>>>(candk, csel2, tidx, ttanh);
  k_gru<<<128, 384, 0, stream>>>(h1, tidx, ttanh, wih2, whh2, bih2, bhh2, h02, WTh, WTl);
  k_gemm4<<<gemmblocks, 256, 0, stream>>>(h1, WTh, WTl, xw, N);
  k_gather<1><<<gatherblocks, 256, 0, stream>>>(xw, dinv, rstart, pay, nullptr, out,
                                                nullptr, nullptr, nullptr, vvec, cc, N);
}

// Round 8
// 415.366 us; speedup vs baseline: 1.3064x; 1.0506x over previous
//
#include <hip/hip_runtime.h>
#include <cstdint>
#include <cstddef>

// ---------------------------------------------------------------------------
// TemporalGNN: 2x EvolveGCNH (TopK-pool -> GRU weight evolve -> GCNConv) + MLP
// N=100000 nodes, F=128, E=625000 edges, all fp32.
// R8: gather edge-loads software-pipelined 8-deep via ordered asm
//     global_load_dwordx2 (compiler was serializing at VGPR=12).
// ---------------------------------------------------------------------------

#define FDIM 128

typedef __attribute__((ext_vector_type(8))) short bfrag;   // 8 bf16 (4 VGPRs)
typedef __attribute__((ext_vector_type(4))) float f32x4;
typedef __attribute__((ext_vector_type(2))) float f32x2;

__device__ __forceinline__ float wave_sum(float v) {
#pragma unroll
  for (int m = 32; m >= 1; m >>= 1) v += __shfl_xor(v, m, 64);
  return v;
}

__device__ __forceinline__ float sigmoidf_(float x) {
  return 1.0f / (1.0f + expf(-x));
}

// monotone float->uint map (order-preserving)
__device__ __forceinline__ unsigned omap(float f) {
  unsigned u = __float_as_uint(f);
  return (u & 0x80000000u) ? ~u : (u | 0x80000000u);
}

// xcd-chunked block remap (requires gridDim.x % 8 == 0)
__device__ __forceinline__ int xcd_chunk(int b, int nb) {
  return (b & 7) * (nb >> 3) + (b >> 3);
}

// LDS byte swizzle: row stride 256B, XOR col bits 4-6 with row&7 -> 2-way max
__device__ __forceinline__ int swz(int row, int colb) {
  return row * 256 + (colb ^ ((row & 7) << 4));
}

// ---------------- setup: degree, CSR build -----------------------------------

__global__ void k_edge_deg(const int* __restrict__ ei, const float* __restrict__ ew,
                           float* deg, int* cnt, int E) {
  int e = blockIdx.x * blockDim.x + threadIdx.x;
  if (e < E) {
    int c = ei[E + e];                         // col
    atomicAdd(&deg[c], ew[e]);
    atomicAdd(&cnt[c], 1);
  }
}

// block sums for cnt (1024/block) + dinv = rsqrt(1 + sum(w)) (self-loop)
__global__ void k_scan1(const int* __restrict__ cnt, int* bsum,
                        const float* __restrict__ deg, float* __restrict__ dinv, int n) {
  __shared__ int s[256];
  int b = blockIdx.x, t = threadIdx.x;
  int base = b * 1024;
  int v = 0;
#pragma unroll
  for (int j = 0; j < 4; j++) {
    int i = base + j * 256 + t;
    if (i < n) { v += cnt[i]; dinv[i] = 1.0f / sqrtf(1.0f + deg[i]); }
  }
  s[t] = v; __syncthreads();
  for (int off = 128; off > 0; off >>= 1) { if (t < off) s[t] += s[t + off]; __syncthreads(); }
  if (t == 0) bsum[b] = s[0];
}

// exclusive scan of bsum in LDS + rstart[N]=E + tiny per-layer setup (merged)
__global__ __launch_bounds__(128) void k_scan2_setup(
    int* bsum, int nb, int* rstartN,
    const float* p1, const float* p2, float* invn1, float* invn2,
    const float* l1w, const float* l1b, const float* l2w, const float* l2b,
    float* v, float* cc) {
  __shared__ int s[1024];
  int t = threadIdx.x;
  for (int i = t; i < nb; i += 128) s[i] = bsum[i];
  __syncthreads();
  if (t == 0) {
    int run = 0;
    for (int b = 0; b < nb; b++) { int x = s[b]; s[b] = run; run += x; }
    s[1023] = run;
  }
  __syncthreads();
  for (int i = t; i < nb; i += 128) bsum[i] = s[i];
  if (t == 0) rstartN[0] = s[1023];
  int wv = t >> 6, l = t & 63;
  const float* p = wv ? p2 : p1;
  float2 pv = ((const float2*)p)[l];
  float ss = wave_sum(pv.x * pv.x + pv.y * pv.y);
  if (l == 0) (wv ? invn2 : invn1)[0] = 1.0f / sqrtf(ss);
  v[t] = l2w[0] * l1w[t] + l2w[1] * l1w[128 + t];
  if (t == 0) cc[0] = l2w[0] * l1b[0] + l2w[1] * l1b[1] + l2b[0];
}

__global__ __launch_bounds__(1024) void k_scan3(const int* __restrict__ cnt,
                                                const int* __restrict__ bsum,
                                                int* rstart, int* rnext, int n) {
  __shared__ int s[1024];
  int b = blockIdx.x, t = threadIdx.x;
  int i = b * 1024 + t;
  int v = (i < n) ? cnt[i] : 0;
  s[t] = v; __syncthreads();
  for (int off = 1; off < 1024; off <<= 1) {
    int tmp = (t >= off) ? s[t - off] : 0;
    __syncthreads();
    s[t] += tmp;
    __syncthreads();
  }
  if (i < n) { int ex = bsum[b] + s[t] - v; rstart[i] = ex; rnext[i] = ex; }
}

// scatter edge payload (row, norm) into CSR slots
__global__ void k_fill(const int* __restrict__ ei, const float* __restrict__ ew,
                       const float* __restrict__ dinv, int* rnext, int2* pay, int E) {
  int e = blockIdx.x * blockDim.x + threadIdx.x;
  if (e < E) {
    int r = ei[e];
    int c = ei[E + e];
    float nm = dinv[r] * ew[e] * dinv[c];
    int pos = atomicAdd(&rnext[c], 1);
    pay[pos] = make_int2(r, __float_as_int(nm));
  }
}

// ---------------- top-k: sample dots -> thr -> fused score+collect -> sel ----

__global__ void k_sampdots(const float* __restrict__ x, const float* __restrict__ p,
                           const float* __restrict__ invn, float* __restrict__ samp,
                           int stride) {
  int l = threadIdx.x & 63;
  int w = blockIdx.x * 4 + (threadIdx.x >> 6);   // 0..511
  float2 pv = ((const float2*)p)[l];
  float inv = invn[0];
#pragma unroll
  for (int r = 0; r < 4; r++) {
    int si = w * 4 + r;
    float2 a = ((const float2*)(x + (size_t)(si * stride) * FDIM))[l];
    float s = wave_sum(a.x * pv.x + a.y * pv.y) * inv;
    if (l == 0) samp[si] = s;
  }
}

// bitonic sort 2048 samples desc, thr = 16th largest
__global__ __launch_bounds__(1024) void k_thr(const float* __restrict__ samp,
                                              float* __restrict__ thr) {
  __shared__ float a[2048];
  int t = threadIdx.x;
  a[t] = samp[t]; a[t + 1024] = samp[t + 1024];
  for (int size = 2; size <= 2048; size <<= 1) {
    for (int st = size >> 1; st > 0; st >>= 1) {
      __syncthreads();
      for (int i = t; i < 2048; i += 1024) {
        int j = i ^ st;
        if (j > i) {
          float xv = a[i], yv = a[j];
          bool up = ((i & size) == 0);
          if (up ? (xv < yv) : (xv > yv)) { a[i] = yv; a[j] = xv; }
        }
      }
    }
  }
  __syncthreads();
  if (t == 0) thr[0] = a[15];
}

// score all rows, collect >= thr directly (no score array)
__global__ void k_scorecollect(const float* __restrict__ x, const float* __restrict__ p,
                               const float* __restrict__ invn, const float* __restrict__ thr,
                               unsigned long long* __restrict__ candk, int* __restrict__ csel,
                               int n) {
  int l = threadIdx.x & 63;
  int eb = xcd_chunk(blockIdx.x, gridDim.x);
  int base = (eb * 4 + (threadIdx.x >> 6)) * 16;
  if (base >= n) return;
  float2 pv = ((const float2*)p)[l];
  float inv = invn[0], th = thr[0];
  int lim = min(16, n - base);
  for (int r = 0; r < lim; r++) {
    float2 a = ((const float2*)(x + (size_t)(base + r) * FDIM))[l];
    float s = wave_sum(a.x * pv.x + a.y * pv.y) * inv;
    if (l == 0 && s >= th) {
      int pos = atomicAdd(csel, 1);
      if (pos < 4096)
        candk[pos] = ((unsigned long long)omap(s) << 32) | (unsigned)(~(unsigned)(base + r));
    }
  }
}

// layer-2: thr from strided samples of the sc array (written by gather<0>)
__global__ __launch_bounds__(1024) void k_sample(const float* __restrict__ sc, int n,
                                                 float* __restrict__ thr) {
  __shared__ float a[2048];
  int t = threadIdx.x;
  int stride = n / 2048;
#pragma unroll
  for (int j = 0; j < 2; j++) a[j * 1024 + t] = sc[(size_t)(j * 1024 + t) * stride];
  for (int size = 2; size <= 2048; size <<= 1) {
    for (int st = size >> 1; st > 0; st >>= 1) {
      __syncthreads();
      for (int i = t; i < 2048; i += 1024) {
        int j = i ^ st;
        if (j > i) {
          float xv = a[i], yv = a[j];
          bool up = ((i & size) == 0);
          if (up ? (xv < yv) : (xv > yv)) { a[i] = yv; a[j] = xv; }
        }
      }
    }
  }
  __syncthreads();
  if (t == 0) thr[0] = a[15];
}

__global__ void k_collect(const float* __restrict__ sc, const float* __restrict__ thr,
                          unsigned long long* candk, int* csel, int n) {
  int i = blockIdx.x * blockDim.x + threadIdx.x;
  if (i >= n) return;
  float s = sc[i];
  if (s >= thr[0]) {
    int pos = atomicAdd(csel, 1);
    if (pos < 4096)
      candk[pos] = ((unsigned long long)omap(s) << 32) | (unsigned)(~(unsigned)i);
  }
}

// sort candidates (desc, index-asc tiebreak baked into key), emit top 128
__global__ __launch_bounds__(1024) void k_sel(const unsigned long long* __restrict__ candk,
                                              const int* __restrict__ csel,
                                              int* tidx, float* ttanh) {
  __shared__ unsigned long long a[4096];
  int t = threadIdx.x;
  int nc = csel[0]; if (nc > 4096) nc = 4096;
  int M = 128; while (M < nc) M <<= 1;
  for (int i = t; i < M; i += 1024) a[i] = (i < nc) ? candk[i] : 0ULL;
  for (int size = 2; size <= M; size <<= 1) {
    for (int stride = size >> 1; stride > 0; stride >>= 1) {
      __syncthreads();
      for (int i = t; i < M; i += 1024) {
        int j = i ^ stride;
        if (j > i) {
          unsigned long long x = a[i], y = a[j];
          bool up = ((i & size) == 0);
          if (up ? (x < y) : (x > y)) { a[i] = y; a[j] = x; }
        }
      }
    }
  }
  __syncthreads();
  if (t < 128) {
    unsigned long long k = a[t];
    unsigned idx = ~(unsigned)k;
    unsigned hi = (unsigned)(k >> 32);
    unsigned u = (hi & 0x80000000u) ? (hi ^ 0x80000000u) : ~hi;
    tidx[t] = (int)idx;
    ttanh[t] = tanhf(__uint_as_float(u));
  }
}

// ---------------- GRU weight evolve -> bf16-split transposed weights --------

__global__ __launch_bounds__(384) void k_gru(const float* __restrict__ xin,
                                             const int* __restrict__ tidx,
                                             const float* __restrict__ ttanh,
                                             const float* __restrict__ wih,
                                             const float* __restrict__ whh,
                                             const float* __restrict__ bih,
                                             const float* __restrict__ bhh,
                                             const float* __restrict__ h0,
                                             unsigned short* __restrict__ WT_hi,
                                             unsigned short* __restrict__ WT_lo) {
  __shared__ float xt[128], hs[128], gis[384], ghs[384];
  int r = blockIdx.x, t = threadIdx.x;
  if (t < 128) {
    int idx = tidx[r];
    xt[t] = xin[(size_t)idx * FDIM + t] * ttanh[r];
    hs[t] = h0[r * FDIM + t];
  }
  __syncthreads();
  float gi = bih[t], gh = bhh[t];
  const float4* wi4 = (const float4*)(wih + (size_t)t * FDIM);
  const float4* wh4 = (const float4*)(whh + (size_t)t * FDIM);
#pragma unroll 8
  for (int k = 0; k < 32; k++) {
    float4 av = wi4[k], bv = wh4[k];
    gi += av.x * xt[4 * k] + av.y * xt[4 * k + 1] + av.z * xt[4 * k + 2] + av.w * xt[4 * k + 3];
    gh += bv.x * hs[4 * k] + bv.y * hs[4 * k + 1] + bv.z * hs[4 * k + 2] + bv.w * hs[4 * k + 3];
  }
  gis[t] = gi; ghs[t] = gh;
  __syncthreads();
  if (t < 128) {
    float rg = sigmoidf_(gis[t] + ghs[t]);
    float zg = sigmoidf_(gis[t + 128] + ghs[t + 128]);
    float ng = tanhf(gis[t + 256] + rg * ghs[t + 256]);
    float w = (1.0f - zg) * ng + zg * hs[t];
    unsigned u = __float_as_uint(w);
    float res = w - __uint_as_float(u & 0xFFFF0000u);
    WT_hi[t * FDIM + r] = (unsigned short)(u >> 16);
    WT_lo[t * FDIM + r] = (unsigned short)(__float_as_uint(res) >> 16);
  }
}

// ---------------- GEMM via MFMA with LDS-staged B ---------------------------

__global__ __launch_bounds__(256) void k_gemm4(const float* __restrict__ X,
                                               const unsigned short* __restrict__ BTh,
                                               const unsigned short* __restrict__ BTl,
                                               float* __restrict__ Y, int nrows) {
  __shared__ unsigned short sBh[128 * 128];   // 32 KB
  __shared__ unsigned short sBl[128 * 128];   // 32 KB
  int tid = threadIdx.x;
  int eb = xcd_chunk(blockIdx.x, gridDim.x);
  int rblk = eb * 128;
  if (rblk >= nrows) return;
  for (int i = tid; i < 2048; i += 256) {
    int row = i >> 4, colb = (i & 15) << 4;
    *(uint4*)((char*)sBh + swz(row, colb)) = ((const uint4*)BTh)[i];
    *(uint4*)((char*)sBl + swz(row, colb)) = ((const uint4*)BTl)[i];
  }
  __syncthreads();
  int wv = tid >> 6, l = tid & 63;
  int lcol = l & 15;
  int kgrp = (l >> 4) * 8;

  for (int tile = 0; tile < 2; tile++) {
    int r0 = rblk + wv * 32 + tile * 16;
    if (r0 >= nrows) break;
    int arow = min(r0 + lcol, nrows - 1);
    f32x4 acc[8];
#pragma unroll
    for (int c = 0; c < 8; c++) acc[c] = (f32x4){0.f, 0.f, 0.f, 0.f};
    const float* xp = X + (size_t)arow * FDIM + kgrp;
#pragma unroll
    for (int ks = 0; ks < 4; ks++) {
      float4 v0 = *(const float4*)(xp + ks * 32);
      float4 v1 = *(const float4*)(xp + ks * 32 + 4);
      float xs[8] = {v0.x, v0.y, v0.z, v0.w, v1.x, v1.y, v1.z, v1.w};
      bfrag ah, al;
#pragma unroll
      for (int i = 0; i < 8; i++) {
        unsigned u = __float_as_uint(xs[i]);
        float res = xs[i] - __uint_as_float(u & 0xFFFF0000u);
        ah[i] = (short)(u >> 16);
        al[i] = (short)(__float_as_uint(res) >> 16);
      }
      int colb = (ks * 32 + kgrp) * 2;
#pragma unroll
      for (int ct = 0; ct < 8; ct++) {
        int off = swz(ct * 16 + lcol, colb);
        bfrag bh = *(const bfrag*)((const char*)sBh + off);
        bfrag bl = *(const bfrag*)((const char*)sBl + off);
        acc[ct] = __builtin_amdgcn_mfma_f32_16x16x32_bf16(ah, bh, acc[ct], 0, 0, 0);
        acc[ct] = __builtin_amdgcn_mfma_f32_16x16x32_bf16(ah, bl, acc[ct], 0, 0, 0);
        acc[ct] = __builtin_amdgcn_mfma_f32_16x16x32_bf16(al, bh, acc[ct], 0, 0, 0);
      }
    }
    int rbase = r0 + (l >> 4) * 4;
#pragma unroll
    for (int ct = 0; ct < 8; ct++) {
      int col = ct * 16 + lcol;
#pragma unroll
      for (int r = 0; r < 4; r++) {
        int row = rbase + r;
        if (row < nrows) Y[(size_t)row * FDIM + col] = acc[ct][r];
      }
    }
  }
}

// ---------------- GCN gather: 8-deep asm-pipelined edge loads ---------------
// FUSE=0: write h1 + layer-2 score.  FUSE=1: final MLP to out.  XCD-chunked.

template <int FUSE>
__global__ void k_gather(const float* __restrict__ xw, const float* __restrict__ dinv,
                         const int* __restrict__ rstart,    // N+1
                         const int2* __restrict__ pay, float* __restrict__ outH,
                         float* __restrict__ outF,
                         const float* __restrict__ p2, const float* __restrict__ invn2,
                         float* __restrict__ sc,
                         const float* __restrict__ vvec, const float* __restrict__ cc,
                         int n) {
  int wv = threadIdx.x >> 6, l = threadIdx.x & 63;
  int eb = xcd_chunk(blockIdx.x, gridDim.x);
  int c = eb * 4 + wv;
  if (c >= n) return;
  float dc = dinv[c];
  float2 v = ((const float2*)(xw + (size_t)c * FDIM))[l];
  float ax = dc * dc * v.x, ay = dc * dc * v.y;
  int st = rstart[c], cn = rstart[c + 1] - st;
  unsigned long long xwb = (unsigned long long)(const char*)xw + ((size_t)l << 3);
  for (int q0 = 0; q0 < cn; q0 += 64) {
    // pad lanes load row c with weight 0 (L1-hot, exact)
    int2 ep = (q0 + l < cn) ? pay[st + q0 + l] : make_int2(c, 0);
    int m = min(64, cn - q0);
    for (int g = 0; g < m; g += 8) {
      unsigned long long addr[8];
      float w[8];
      f32x2 ev[8];
#pragma unroll
      for (int u = 0; u < 8; u++) {
        int r = __shfl(ep.x, g + u, 64);
        w[u] = __int_as_float(__shfl(ep.y, g + u, 64));
        addr[u] = xwb + ((unsigned long long)(unsigned)r << 9);
      }
#pragma unroll
      for (int u = 0; u < 8; u++)
        asm volatile("global_load_dwordx2 %0, %1, off" : "=v"(ev[u]) : "v"(addr[u]));
      asm volatile("s_waitcnt vmcnt(0)" ::: "memory");
      __builtin_amdgcn_sched_barrier(0);
#pragma unroll
      for (int u = 0; u < 8; u++) { ax += w[u] * ev[u][0]; ay += w[u] * ev[u][1]; }
    }
  }
  float r0 = fmaxf(ax, 0.0f), r1 = fmaxf(ay, 0.0f);
  if (FUSE == 0) {
    ((float2*)(outH + (size_t)c * FDIM))[l] = make_float2(r0, r1);
    float2 pv = ((const float2*)p2)[l];
    float s = wave_sum(r0 * pv.x + r1 * pv.y);
    if (l == 0) sc[c] = s * invn2[0];
  } else {
    float2 vv = ((const float2*)vvec)[l];
    float s = wave_sum(r0 * vv.x + r1 * vv.y);
    if (l == 0) outF[c] = s + cc[0];
  }
}

// ---------------------------------------------------------------------------

extern "C" void kernel_launch(void* const* d_in, const int* in_sizes, int n_in,
                              void* d_out, int out_size, void* d_ws, size_t ws_size,
                              hipStream_t stream) {
  const float* x    = (const float*)d_in[0];
  const int*   ei   = (const int*)d_in[1];
  const float* ew   = (const float*)d_in[2];
  const float* p1   = (const float*)d_in[3];
  const float* wih1 = (const float*)d_in[4];
  const float* whh1 = (const float*)d_in[5];
  const float* bih1 = (const float*)d_in[6];
  const float* bhh1 = (const float*)d_in[7];
  const float* h01  = (const float*)d_in[8];
  const float* p2   = (const float*)d_in[9];
  const float* wih2 = (const float*)d_in[10];
  const float* whh2 = (const float*)d_in[11];
  const float* bih2 = (const float*)d_in[12];
  const float* bhh2 = (const float*)d_in[13];
  const float* h02  = (const float*)d_in[14];
  const float* l1w  = (const float*)d_in[15];
  const float* l1b  = (const float*)d_in[16];
  const float* l2w  = (const float*)d_in[17];
  const float* l2b  = (const float*)d_in[18];
  float* out = (float*)d_out;

  const int N = in_sizes[0] / FDIM;
  const int E = in_sizes[2];

  // workspace layout
  size_t off = 0;
  auto alloc = [&](size_t bytes) -> char* {
    char* p = (char*)d_ws + off;
    off = (off + bytes + 255) & ~(size_t)255;
    return p;
  };
  // zero-init region (one memset): deg, cnt, csel1/2
  float* deg   = (float*)alloc((size_t)N * 4);
  int*   cnt   = (int*)alloc((size_t)N * 4);
  int*   csel1 = (int*)alloc(8);
  int*   csel2 = (int*)alloc(8);
  size_t zero_span = (size_t)((char*)(csel2 + 2) - (char*)deg);
  // rest
  float* scores = (float*)alloc((size_t)N * 4);     // layer-2 sc only
  unsigned long long* candk = (unsigned long long*)alloc(4096 * 8);
  int*   tidx  = (int*)alloc(128 * 4);
  float* ttanh = (float*)alloc(128 * 4);
  float* invn1 = (float*)alloc(4);
  float* invn2 = (float*)alloc(4);
  float* thr1  = (float*)alloc(4);
  float* thr2  = (float*)alloc(4);
  float* samp  = (float*)alloc(2048 * 4);
  float* dinv  = (float*)alloc((size_t)N * 4);
  int*   rstart= (int*)alloc((size_t)(N + 1) * 4);
  int*   rnext = (int*)alloc((size_t)N * 4);
  const int nb = (N + 1023) / 1024;
  int*   bsum  = (int*)alloc((size_t)nb * 4);
  int2*  pay   = (int2*)alloc((size_t)E * 8);
  float* vvec  = (float*)alloc(128 * 4);
  float* cc    = (float*)alloc(4);
  unsigned short* WTh = (unsigned short*)alloc(128 * 128 * 2);
  unsigned short* WTl = (unsigned short*)alloc(128 * 128 * 2);
  float* xw    = (float*)alloc((size_t)N * FDIM * 4);
  float* h1    = (float*)alloc((size_t)N * FDIM * 4);
  (void)ws_size; (void)n_in; (void)out_size;

  const int scoreblocks  = (((N + 15) / 16 + 3) / 4 + 7) & ~7;   // mult of 8
  const int gemmblocks   = ((N + 127) / 128 + 7) & ~7;           // 128 rows/blk
  const int gatherblocks = (N + 3) / 4;                          // %8 == 0
  const int sampstride   = N / 2048;

  // ---- setup ----
  hipMemsetAsync(deg, 0, zero_span, stream);
  k_edge_deg<<<(E + 255) / 256, 256, 0, stream>>>(ei, ew, deg, cnt, E);
  k_scan1<<<nb, 256, 0, stream>>>(cnt, bsum, deg, dinv, N);
  k_scan2_setup<<<1, 128, 0, stream>>>(bsum, nb, rstart + N, p1, p2, invn1, invn2,
                                       l1w, l1b, l2w, l2b, vvec, cc);
  k_scan3<<<nb, 1024, 0, stream>>>(cnt, bsum, rstart, rnext, N);
  k_fill<<<(E + 255) / 256, 256, 0, stream>>>(ei, ew, dinv, rnext, pay, E);

  // ---- layer 1 ----
  k_sampdots<<<128, 256, 0, stream>>>(x, p1, invn1, samp, sampstride);
  k_thr<<<1, 1024, 0, stream>>>(samp, thr1);
  k_scorecollect<<<scoreblocks, 256, 0, stream>>>(x, p1, invn1, thr1, candk, csel1, N);
  k_sel<<<1, 1024, 0, stream>>>(candk, csel1, tidx, ttanh);
  k_gru<<<128, 384, 0, stream>>>(x, tidx, ttanh, wih1, whh1, bih1, bhh1, h01, WTh, WTl);
  k_gemm4<<<gemmblocks, 256, 0, stream>>>(x, WTh, WTl, xw, N);
  k_gather<0><<<gatherblocks, 256, 0, stream>>>(xw, dinv, rstart, pay, h1, nullptr,
                                                p2, invn2, scores, nullptr, nullptr, N);

  // ---- layer 2 + fused final linear ----
  k_sample<<<1, 1024, 0, stream>>>(scores, N, thr2);
  k_collect<<<(N + 255) / 256, 256, 0, stream>>>(scores, thr2, candk, csel2, N);
  k_sel<<<1, 1024, 0, stream>>>(candk, csel2, tidx, ttanh);
  k_gru<<<128, 384, 0, stream>>>(h1, tidx, ttanh, wih2, whh2, bih2, bhh2, h02, WTh, WTl);
  k_gemm4<<<gemmblocks, 256, 0, stream>>>(h1, WTh, WTl, xw, N);
  k_gather<1><<<gatherblocks, 256, 0, stream>>>(xw, dinv, rstart, pay, nullptr, out,
                                                nullptr, nullptr, nullptr, vvec, cc, N);
}